// Round 1
// baseline (2286.948 us; speedup 1.0000x reference)
//
#include <hip/hip_runtime.h>
#include <hip/hip_bf16.h>
#include <math.h>

// ---------------- CSR build ----------------

__global__ __launch_bounds__(256) void k_hist(const int* __restrict__ dst, int* __restrict__ cnt, int E) {
    int i = blockIdx.x * blockDim.x + threadIdx.x;
    if (i < E) atomicAdd(&cnt[dst[i]], 1);
}

__global__ __launch_bounds__(256) void k_scanA(const int* __restrict__ cnt, int* __restrict__ bsum, int N) {
    __shared__ int s[256];
    int t = threadIdx.x;
    int i = blockIdx.x * 256 + t;
    s[t] = (i < N) ? cnt[i] : 0;
    __syncthreads();
    for (int off = 128; off > 0; off >>= 1) {
        if (t < off) s[t] += s[t + off];
        __syncthreads();
    }
    if (t == 0) bsum[blockIdx.x] = s[0];
}

__global__ __launch_bounds__(512) void k_scanB(int* __restrict__ bsum, int B) {
    __shared__ int s[512];
    int t = threadIdx.x;
    int v = (t < B) ? bsum[t] : 0;
    s[t] = v;
    __syncthreads();
    for (int off = 1; off < 512; off <<= 1) {
        int x = (t >= off) ? s[t - off] : 0;
        __syncthreads();
        s[t] += x;
        __syncthreads();
    }
    if (t < B) bsum[t] = s[t] - v;   // exclusive
}

__global__ __launch_bounds__(256) void k_scanC(const int* __restrict__ cnt, const int* __restrict__ bsum,
                                               int* __restrict__ row_off, int* __restrict__ cursor,
                                               float* __restrict__ dinv, int N, int E) {
    __shared__ int s[256];
    int t = threadIdx.x;
    int i = blockIdx.x * 256 + t;
    int v = (i < N) ? cnt[i] : 0;
    s[t] = v;
    __syncthreads();
    for (int off = 1; off < 256; off <<= 1) {
        int x = (t >= off) ? s[t - off] : 0;
        __syncthreads();
        s[t] += x;
        __syncthreads();
    }
    if (i < N) {
        int excl = bsum[blockIdx.x] + s[t] - v;
        row_off[i] = excl;
        cursor[i]  = excl;
        dinv[i]    = rsqrtf((float)(v > 1 ? v : 1));
    }
    if (i == 0) row_off[N] = E;
}

__global__ __launch_bounds__(256) void k_scatter(const int* __restrict__ src, const int* __restrict__ dst,
                                                 int* __restrict__ cursor, int* __restrict__ csr, int E) {
    int i = blockIdx.x * blockDim.x + threadIdx.x;
    if (i < E) {
        int d = dst[i];
        int pos = atomicAdd(&cursor[d], 1);
        csr[pos] = src[i];
    }
}

// ---------------- Chebyshev aggregation: out = alpha * (dinv[n] * sum_j X[j]*dinv[j]) + beta * Z[n] ----------------

template <int D>
__global__ __launch_bounds__(256) void k_aggr(const float* __restrict__ X, const float* __restrict__ Z,
                                              const float* __restrict__ dinv,
                                              const int* __restrict__ row_off, const int* __restrict__ csr,
                                              float* __restrict__ out, float alpha, float beta, int N) {
    int t = blockIdx.x * blockDim.x + threadIdx.x;
    int node = t / D;
    int d = t % D;
    if (node >= N) return;
    int beg = row_off[node], end = row_off[node + 1];
    float a0 = 0.f, a1 = 0.f, a2 = 0.f, a3 = 0.f;
    int j = beg;
    for (; j + 3 < end; j += 4) {
        int s0 = csr[j], s1 = csr[j + 1], s2 = csr[j + 2], s3 = csr[j + 3];
        a0 += X[s0 * D + d] * dinv[s0];
        a1 += X[s1 * D + d] * dinv[s1];
        a2 += X[s2 * D + d] * dinv[s2];
        a3 += X[s3 * D + d] * dinv[s3];
    }
    for (; j < end; ++j) {
        int s = csr[j];
        a0 += X[s * D + d] * dinv[s];
    }
    float acc = (a0 + a1) + (a2 + a3);
    float v = alpha * dinv[node] * acc;
    if (Z) v += beta * Z[node * D + d];
    out[node * D + d] = v;
}

// ---------------- Cheb matmul: out = relu(b + X0@W[0] + X1@W[1] + X2@W[2]), W[k][i][o] ----------------

template <int K>
__global__ __launch_bounds__(256) void k_cheb_mm(const float* __restrict__ X0, const float* __restrict__ X1,
                                                 const float* __restrict__ X2, const float* __restrict__ W,
                                                 const float* __restrict__ b, float* __restrict__ out, int N) {
    __shared__ float Ws[3 * K * 64];
    int t = threadIdx.x;
    for (int idx = t; idx < 3 * K * 64; idx += 256) Ws[idx] = W[idx];
    __syncthreads();
    int wave = t >> 6, lane = t & 63;
    int node = blockIdx.x * 4 + wave;
    if (node >= N) return;
    float v0 = 0.f, v1 = 0.f, v2 = 0.f;
    if (lane < K) {
        v0 = X0[node * K + lane];
        v1 = X1[node * K + lane];
        v2 = X2[node * K + lane];
    }
    float acc = b[lane];
#pragma unroll
    for (int i = 0; i < K; ++i) {
        float x0 = __shfl(v0, i), x1 = __shfl(v1, i), x2 = __shfl(v2, i);
        acc += x0 * Ws[i * 64 + lane] + x1 * Ws[(K + i) * 64 + lane] + x2 * Ws[(2 * K + i) * 64 + lane];
    }
    out[node * 64 + lane] = fmaxf(acc, 0.f);
}

// ---------------- EdgeConv stage 1: m = X@Wt ; p = X@(Wt+Wp) + bt + bp ----------------

__global__ __launch_bounds__(256) void k_e1(const float* __restrict__ X, const float* __restrict__ Wt,
                                            const float* __restrict__ Wp, const float* __restrict__ bt,
                                            const float* __restrict__ bp, float* __restrict__ m,
                                            float* __restrict__ pbuf, int N) {
    __shared__ float Wts[64 * 64];
    __shared__ float Wps[64 * 64];
    int t = threadIdx.x;
    for (int idx = t; idx < 4096; idx += 256) {
        Wts[idx] = Wt[idx];
        Wps[idx] = Wp[idx];
    }
    __syncthreads();
    int wave = t >> 6, lane = t & 63;
    int node = blockIdx.x * 4 + wave;
    if (node >= N) return;
    float v = X[node * 64 + lane];
    float am = 0.f, ap = bt[lane] + bp[lane];
#pragma unroll
    for (int i = 0; i < 64; ++i) {
        float xi = __shfl(v, i);
        float wt = Wts[i * 64 + lane];
        am += xi * wt;
        ap += xi * (wt + Wps[i * 64 + lane]);
    }
    m[node * 64 + lane] = am;
    pbuf[node * 64 + lane] = ap;
}

// ---------------- EdgeConv stage 2: out = relu(p[n] + max_j(-m[src_j])), 0 if no in-edges ----------------

__global__ __launch_bounds__(256) void k_e2(const float* __restrict__ m, const float* __restrict__ pbuf,
                                            const int* __restrict__ row_off, const int* __restrict__ csr,
                                            float* __restrict__ out, int N) {
    int t = blockIdx.x * blockDim.x + threadIdx.x;
    int node = t >> 6;
    int d = t & 63;
    if (node >= N) return;
    int beg = row_off[node], end = row_off[node + 1];
    float a0 = -INFINITY, a1 = -INFINITY, a2 = -INFINITY, a3 = -INFINITY;
    int j = beg;
    for (; j + 3 < end; j += 4) {
        int s0 = csr[j], s1 = csr[j + 1], s2 = csr[j + 2], s3 = csr[j + 3];
        a0 = fmaxf(a0, -m[s0 * 64 + d]);
        a1 = fmaxf(a1, -m[s1 * 64 + d]);
        a2 = fmaxf(a2, -m[s2 * 64 + d]);
        a3 = fmaxf(a3, -m[s3 * 64 + d]);
    }
    for (; j < end; ++j) {
        int s = csr[j];
        a0 = fmaxf(a0, -m[s * 64 + d]);
    }
    float r = 0.f;
    if (end > beg) r = fmaxf(pbuf[node * 64 + d] + fmaxf(fmaxf(a0, a1), fmaxf(a2, a3)), 0.f);
    out[node * 64 + d] = r;
}

// ---------------- graph mean pooling ----------------

__global__ __launch_bounds__(256) void k_pool(const float* __restrict__ h, const int* __restrict__ gid,
                                              float* __restrict__ out, float* __restrict__ gcnt, int N) {
    int t = blockIdx.x * blockDim.x + threadIdx.x;
    int node = t >> 6, d = t & 63;
    if (node >= N) return;
    int g = gid[node];
    atomicAdd(&out[g * 64 + d], h[node * 64 + d]);
    if (d == 0) atomicAdd(&gcnt[g], 1.f);
}

__global__ __launch_bounds__(256) void k_div(float* __restrict__ out, const float* __restrict__ gcnt, int total) {
    int i = blockIdx.x * blockDim.x + threadIdx.x;
    if (i < total) out[i] /= fmaxf(gcnt[i >> 6], 1.f);
}

// ---------------- launcher ----------------

extern "C" void kernel_launch(void* const* d_in, const int* in_sizes, int n_in,
                              void* d_out, int out_size, void* d_ws, size_t ws_size,
                              hipStream_t stream) {
    const float* feat = (const float*)d_in[0];
    const int* src = (const int*)d_in[1];
    const int* dst = (const int*)d_in[2];
    const int* gid = (const int*)d_in[3];
    const float* W1 = (const float*)d_in[4];  const float* b1 = (const float*)d_in[5];
    const float* W2 = (const float*)d_in[6];  const float* b2 = (const float*)d_in[7];
    const float* W3 = (const float*)d_in[8];  const float* b3 = (const float*)d_in[9];
    const float* Wt1 = (const float*)d_in[10]; const float* bt1 = (const float*)d_in[11];
    const float* Wp1 = (const float*)d_in[12]; const float* bp1 = (const float*)d_in[13];
    const float* Wt2 = (const float*)d_in[14]; const float* bt2 = (const float*)d_in[15];
    const float* Wp2 = (const float*)d_in[16]; const float* bp2 = (const float*)d_in[17];
    float* out = (float*)d_out;

    const int N = in_sizes[0] / 16;
    const int E = in_sizes[1];
    const int G = out_size / 64;

    char* p = (char*)d_ws;
    auto alloc = [&](size_t nbytes) {
        void* r = (void*)p;
        p += (nbytes + 255) & ~(size_t)255;
        return r;
    };
    int* cnt      = (int*)alloc((size_t)N * 4);
    int* row_off  = (int*)alloc((size_t)(N + 1) * 4);
    int* cursor   = (int*)alloc((size_t)N * 4);
    int* csr      = (int*)alloc((size_t)E * 4);
    int* bsum     = (int*)alloc(512 * 4);
    float* dinv   = (float*)alloc((size_t)N * 4);
    float* bufA   = (float*)alloc((size_t)N * 64 * 4);
    float* bufB   = (float*)alloc((size_t)N * 64 * 4);
    float* bufC   = (float*)alloc((size_t)N * 64 * 4);
    float* bufD   = (float*)alloc((size_t)N * 64 * 4);
    float* gcnt   = (float*)alloc((size_t)G * 4);

    hipMemsetAsync(cnt, 0, (size_t)N * 4, stream);
    hipMemsetAsync(gcnt, 0, (size_t)G * 4, stream);
    hipMemsetAsync(d_out, 0, (size_t)out_size * 4, stream);

    const int B = (N + 255) / 256;         // scan blocks (<=512 required)
    const int ebk = (E + 255) / 256;
    const int nb64 = (N * 64 + 255) / 256; // wave-per-node kernels
    const int nb16 = (N * 16 + 255) / 256;
    const int nbw = (N + 3) / 4;           // 4 nodes (waves) per 256-block

    k_hist<<<ebk, 256, 0, stream>>>(dst, cnt, E);
    k_scanA<<<B, 256, 0, stream>>>(cnt, bsum, N);
    k_scanB<<<1, 512, 0, stream>>>(bsum, B);
    k_scanC<<<B, 256, 0, stream>>>(cnt, bsum, row_off, cursor, dinv, N, E);
    k_scatter<<<ebk, 256, 0, stream>>>(src, dst, cursor, csr, E);

    // ---- Cheb layer 1 (IN=16) : X1 = -aggr(X0); X2 = -2*aggr(X1) - X0
    k_aggr<16><<<nb16, 256, 0, stream>>>(feat, nullptr, dinv, row_off, csr, bufA, -1.f, 0.f, N);
    k_aggr<16><<<nb16, 256, 0, stream>>>(bufA, feat, dinv, row_off, csr, bufB, -2.f, -1.f, N);
    k_cheb_mm<16><<<nbw, 256, 0, stream>>>(feat, bufA, bufB, W1, b1, bufC, N);

    // ---- EdgeConv 1
    k_e1<<<nbw, 256, 0, stream>>>(bufC, Wt1, Wp1, bt1, bp1, bufA, bufB, N);
    k_e2<<<nb64, 256, 0, stream>>>(bufA, bufB, row_off, csr, bufD, N);

    // ---- Cheb layer 2
    k_aggr<64><<<nb64, 256, 0, stream>>>(bufD, nullptr, dinv, row_off, csr, bufA, -1.f, 0.f, N);
    k_aggr<64><<<nb64, 256, 0, stream>>>(bufA, bufD, dinv, row_off, csr, bufB, -2.f, -1.f, N);
    k_cheb_mm<64><<<nbw, 256, 0, stream>>>(bufD, bufA, bufB, W2, b2, bufC, N);

    // ---- EdgeConv 2
    k_e1<<<nbw, 256, 0, stream>>>(bufC, Wt2, Wp2, bt2, bp2, bufA, bufB, N);
    k_e2<<<nb64, 256, 0, stream>>>(bufA, bufB, row_off, csr, bufD, N);

    // ---- Cheb layer 3
    k_aggr<64><<<nb64, 256, 0, stream>>>(bufD, nullptr, dinv, row_off, csr, bufA, -1.f, 0.f, N);
    k_aggr<64><<<nb64, 256, 0, stream>>>(bufA, bufD, dinv, row_off, csr, bufB, -2.f, -1.f, N);
    k_cheb_mm<64><<<nbw, 256, 0, stream>>>(bufD, bufA, bufB, W3, b3, bufC, N);

    // ---- per-graph mean pooling
    k_pool<<<nbw, 256, 0, stream>>>(bufC, gid, out, gcnt, N);
    k_div<<<(out_size + 255) / 256, 256, 0, stream>>>(out, gcnt, out_size);
}

// Round 2
// 1735.671 us; speedup vs baseline: 1.3176x; 1.3176x over previous
//
#include <hip/hip_runtime.h>
#include <hip/hip_bf16.h>
#include <math.h>

// ---------------- CSR build ----------------

__global__ __launch_bounds__(256) void k_hist(const int* __restrict__ dst, int* __restrict__ cnt, int E) {
    int i = blockIdx.x * blockDim.x + threadIdx.x;
    if (i < E) atomicAdd(&cnt[dst[i]], 1);
}

__global__ __launch_bounds__(256) void k_scanA(const int* __restrict__ cnt, int* __restrict__ bsum, int N) {
    __shared__ int s[256];
    int t = threadIdx.x;
    int i = blockIdx.x * 256 + t;
    s[t] = (i < N) ? cnt[i] : 0;
    __syncthreads();
    for (int off = 128; off > 0; off >>= 1) {
        if (t < off) s[t] += s[t + off];
        __syncthreads();
    }
    if (t == 0) bsum[blockIdx.x] = s[0];
}

__global__ __launch_bounds__(512) void k_scanB(int* __restrict__ bsum, int B) {
    __shared__ int s[512];
    int t = threadIdx.x;
    int v = (t < B) ? bsum[t] : 0;
    s[t] = v;
    __syncthreads();
    for (int off = 1; off < 512; off <<= 1) {
        int x = (t >= off) ? s[t - off] : 0;
        __syncthreads();
        s[t] += x;
        __syncthreads();
    }
    if (t < B) bsum[t] = s[t] - v;   // exclusive
}

__global__ __launch_bounds__(256) void k_scanC(const int* __restrict__ cnt, const int* __restrict__ bsum,
                                               int* __restrict__ row_off, int* __restrict__ cursor,
                                               float* __restrict__ dinv, int N, int E) {
    __shared__ int s[256];
    int t = threadIdx.x;
    int i = blockIdx.x * 256 + t;
    int v = (i < N) ? cnt[i] : 0;
    s[t] = v;
    __syncthreads();
    for (int off = 1; off < 256; off <<= 1) {
        int x = (t >= off) ? s[t - off] : 0;
        __syncthreads();
        s[t] += x;
        __syncthreads();
    }
    if (i < N) {
        int excl = bsum[blockIdx.x] + s[t] - v;
        row_off[i] = excl;
        cursor[i]  = excl;
        dinv[i]    = rsqrtf((float)(v > 1 ? v : 1));
    }
    if (i == 0) row_off[N] = E;
}

__global__ __launch_bounds__(256) void k_scatter(const int* __restrict__ src, const int* __restrict__ dst,
                                                 int* __restrict__ cursor, int* __restrict__ csr, int E) {
    int i = blockIdx.x * blockDim.x + threadIdx.x;
    if (i < E) {
        int d = dst[i];
        int pos = atomicAdd(&cursor[d], 1);
        csr[pos] = src[i];
    }
}

// ---------------- Chebyshev aggregation: out = alpha * (dinv[n] * sum_j X[j]*dinv[j]) + beta * Z[n] ----------------

template <int D>
__global__ __launch_bounds__(256) void k_aggr(const float* __restrict__ X, const float* __restrict__ Z,
                                              const float* __restrict__ dinv,
                                              const int* __restrict__ row_off, const int* __restrict__ csr,
                                              float* __restrict__ out, float alpha, float beta, int N) {
    int t = blockIdx.x * blockDim.x + threadIdx.x;
    int node = t / D;
    int d = t % D;
    if (node >= N) return;
    int beg = row_off[node], end = row_off[node + 1];
    float a0 = 0.f, a1 = 0.f, a2 = 0.f, a3 = 0.f;
    int j = beg;
    for (; j + 3 < end; j += 4) {
        int s0 = csr[j], s1 = csr[j + 1], s2 = csr[j + 2], s3 = csr[j + 3];
        a0 += X[s0 * D + d] * dinv[s0];
        a1 += X[s1 * D + d] * dinv[s1];
        a2 += X[s2 * D + d] * dinv[s2];
        a3 += X[s3 * D + d] * dinv[s3];
    }
    for (; j < end; ++j) {
        int s = csr[j];
        a0 += X[s * D + d] * dinv[s];
    }
    float acc = (a0 + a1) + (a2 + a3);
    float v = alpha * dinv[node] * acc;
    if (Z) v += beta * Z[node * D + d];
    out[node * D + d] = v;
}

// ---------------- Cheb matmul: out = relu(b + X0@W[0] + X1@W[1] + X2@W[2]), W[k][i][o] ----------------

template <int K>
__global__ __launch_bounds__(256) void k_cheb_mm(const float* __restrict__ X0, const float* __restrict__ X1,
                                                 const float* __restrict__ X2, const float* __restrict__ W,
                                                 const float* __restrict__ b, float* __restrict__ out, int N) {
    __shared__ float Ws[3 * K * 64];
    int t = threadIdx.x;
    for (int idx = t; idx < 3 * K * 64; idx += 256) Ws[idx] = W[idx];
    __syncthreads();
    int wave = t >> 6, lane = t & 63;
    int node = blockIdx.x * 4 + wave;
    if (node >= N) return;
    float v0 = 0.f, v1 = 0.f, v2 = 0.f;
    if (lane < K) {
        v0 = X0[node * K + lane];
        v1 = X1[node * K + lane];
        v2 = X2[node * K + lane];
    }
    float acc = b[lane];
#pragma unroll
    for (int i = 0; i < K; ++i) {
        float x0 = __shfl(v0, i), x1 = __shfl(v1, i), x2 = __shfl(v2, i);
        acc += x0 * Ws[i * 64 + lane] + x1 * Ws[(K + i) * 64 + lane] + x2 * Ws[(2 * K + i) * 64 + lane];
    }
    out[node * 64 + lane] = fmaxf(acc, 0.f);
}

// ---------------- EdgeConv stage 1: m = X@Wt ; p = X@(Wt+Wp) + bt + bp ----------------

__global__ __launch_bounds__(256) void k_e1(const float* __restrict__ X, const float* __restrict__ Wt,
                                            const float* __restrict__ Wp, const float* __restrict__ bt,
                                            const float* __restrict__ bp, float* __restrict__ m,
                                            float* __restrict__ pbuf, int N) {
    __shared__ float Wts[64 * 64];
    __shared__ float Wps[64 * 64];
    int t = threadIdx.x;
    for (int idx = t; idx < 4096; idx += 256) {
        Wts[idx] = Wt[idx];
        Wps[idx] = Wp[idx];
    }
    __syncthreads();
    int wave = t >> 6, lane = t & 63;
    int node = blockIdx.x * 4 + wave;
    if (node >= N) return;
    float v = X[node * 64 + lane];
    float am = 0.f, ap = bt[lane] + bp[lane];
#pragma unroll
    for (int i = 0; i < 64; ++i) {
        float xi = __shfl(v, i);
        float wt = Wts[i * 64 + lane];
        am += xi * wt;
        ap += xi * (wt + Wps[i * 64 + lane]);
    }
    m[node * 64 + lane] = am;
    pbuf[node * 64 + lane] = ap;
}

// ---------------- EdgeConv stage 2: out = relu(p[n] + max_j(-m[src_j])), 0 if no in-edges ----------------

__global__ __launch_bounds__(256) void k_e2(const float* __restrict__ m, const float* __restrict__ pbuf,
                                            const int* __restrict__ row_off, const int* __restrict__ csr,
                                            float* __restrict__ out, int N) {
    int t = blockIdx.x * blockDim.x + threadIdx.x;
    int node = t >> 6;
    int d = t & 63;
    if (node >= N) return;
    int beg = row_off[node], end = row_off[node + 1];
    float a0 = -INFINITY, a1 = -INFINITY, a2 = -INFINITY, a3 = -INFINITY;
    int j = beg;
    for (; j + 3 < end; j += 4) {
        int s0 = csr[j], s1 = csr[j + 1], s2 = csr[j + 2], s3 = csr[j + 3];
        a0 = fmaxf(a0, -m[s0 * 64 + d]);
        a1 = fmaxf(a1, -m[s1 * 64 + d]);
        a2 = fmaxf(a2, -m[s2 * 64 + d]);
        a3 = fmaxf(a3, -m[s3 * 64 + d]);
    }
    for (; j < end; ++j) {
        int s = csr[j];
        a0 = fmaxf(a0, -m[s * 64 + d]);
    }
    float r = 0.f;
    if (end > beg) r = fmaxf(pbuf[node * 64 + d] + fmaxf(fmaxf(a0, a1), fmaxf(a2, a3)), 0.f);
    out[node * 64 + d] = r;
}

// ---------------- graph mean pooling (segmented: gid is sorted) ----------------
// One wave per 128-node contiguous chunk; lane = dim. Register-accumulate runs,
// flush one atomic per run boundary -> ~55k atomics instead of 6.4M.

__global__ __launch_bounds__(256) void k_pool(const float* __restrict__ h, const int* __restrict__ gid,
                                              float* __restrict__ out, float* __restrict__ gcnt, int N) {
    const int CHUNK = 128;
    int wave = blockIdx.x * 4 + (threadIdx.x >> 6);
    int lane = threadIdx.x & 63;
    int beg = wave * CHUNK;
    if (beg >= N) return;
    int end = beg + CHUNK < N ? beg + CHUNK : N;
    int gcur = gid[beg];
    float acc = 0.f;
    int cnt = 0;
    for (int n = beg; n < end; ++n) {
        int g = gid[n];                       // wave-uniform broadcast load
        float v = h[n * 64 + lane];
        if (g != gcur) {
            atomicAdd(&out[gcur * 64 + lane], acc);
            if (lane == 0) atomicAdd(&gcnt[gcur], (float)cnt);
            gcur = g; acc = 0.f; cnt = 0;
        }
        acc += v;
        ++cnt;
    }
    atomicAdd(&out[gcur * 64 + lane], acc);
    if (lane == 0) atomicAdd(&gcnt[gcur], (float)cnt);
}

__global__ __launch_bounds__(256) void k_div(float* __restrict__ out, const float* __restrict__ gcnt, int total) {
    int i = blockIdx.x * blockDim.x + threadIdx.x;
    if (i < total) out[i] /= fmaxf(gcnt[i >> 6], 1.f);
}

// ---------------- launcher ----------------

extern "C" void kernel_launch(void* const* d_in, const int* in_sizes, int n_in,
                              void* d_out, int out_size, void* d_ws, size_t ws_size,
                              hipStream_t stream) {
    const float* feat = (const float*)d_in[0];
    const int* src = (const int*)d_in[1];
    const int* dst = (const int*)d_in[2];
    const int* gid = (const int*)d_in[3];
    const float* W1 = (const float*)d_in[4];  const float* b1 = (const float*)d_in[5];
    const float* W2 = (const float*)d_in[6];  const float* b2 = (const float*)d_in[7];
    const float* W3 = (const float*)d_in[8];  const float* b3 = (const float*)d_in[9];
    const float* Wt1 = (const float*)d_in[10]; const float* bt1 = (const float*)d_in[11];
    const float* Wp1 = (const float*)d_in[12]; const float* bp1 = (const float*)d_in[13];
    const float* Wt2 = (const float*)d_in[14]; const float* bt2 = (const float*)d_in[15];
    const float* Wp2 = (const float*)d_in[16]; const float* bp2 = (const float*)d_in[17];
    float* out = (float*)d_out;

    const int N = in_sizes[0] / 16;
    const int E = in_sizes[1];
    const int G = out_size / 64;

    char* p = (char*)d_ws;
    auto alloc = [&](size_t nbytes) {
        void* r = (void*)p;
        p += (nbytes + 255) & ~(size_t)255;
        return r;
    };
    int* cnt      = (int*)alloc((size_t)N * 4);
    int* row_off  = (int*)alloc((size_t)(N + 1) * 4);
    int* cursor   = (int*)alloc((size_t)N * 4);
    int* csr      = (int*)alloc((size_t)E * 4);
    int* bsum     = (int*)alloc(512 * 4);
    float* dinv   = (float*)alloc((size_t)N * 4);
    float* bufA   = (float*)alloc((size_t)N * 64 * 4);
    float* bufB   = (float*)alloc((size_t)N * 64 * 4);
    float* bufC   = (float*)alloc((size_t)N * 64 * 4);
    float* bufD   = (float*)alloc((size_t)N * 64 * 4);
    float* gcnt   = (float*)alloc((size_t)G * 4);

    hipMemsetAsync(cnt, 0, (size_t)N * 4, stream);
    hipMemsetAsync(gcnt, 0, (size_t)G * 4, stream);
    hipMemsetAsync(d_out, 0, (size_t)out_size * 4, stream);

    const int B = (N + 255) / 256;         // scan blocks (<=512 required)
    const int ebk = (E + 255) / 256;
    const int nb64 = (N * 64 + 255) / 256; // wave-per-node kernels
    const int nb16 = (N * 16 + 255) / 256;
    const int nbw = (N + 3) / 4;           // 4 nodes (waves) per 256-block
    const int npool = ((N + 127) / 128 + 3) / 4;

    k_hist<<<ebk, 256, 0, stream>>>(dst, cnt, E);
    k_scanA<<<B, 256, 0, stream>>>(cnt, bsum, N);
    k_scanB<<<1, 512, 0, stream>>>(bsum, B);
    k_scanC<<<B, 256, 0, stream>>>(cnt, bsum, row_off, cursor, dinv, N, E);
    k_scatter<<<ebk, 256, 0, stream>>>(src, dst, cursor, csr, E);

    // ---- Cheb layer 1 (IN=16) : X1 = -aggr(X0); X2 = -2*aggr(X1) - X0
    k_aggr<16><<<nb16, 256, 0, stream>>>(feat, nullptr, dinv, row_off, csr, bufA, -1.f, 0.f, N);
    k_aggr<16><<<nb16, 256, 0, stream>>>(bufA, feat, dinv, row_off, csr, bufB, -2.f, -1.f, N);
    k_cheb_mm<16><<<nbw, 256, 0, stream>>>(feat, bufA, bufB, W1, b1, bufC, N);

    // ---- EdgeConv 1
    k_e1<<<nbw, 256, 0, stream>>>(bufC, Wt1, Wp1, bt1, bp1, bufA, bufB, N);
    k_e2<<<nb64, 256, 0, stream>>>(bufA, bufB, row_off, csr, bufD, N);

    // ---- Cheb layer 2
    k_aggr<64><<<nb64, 256, 0, stream>>>(bufD, nullptr, dinv, row_off, csr, bufA, -1.f, 0.f, N);
    k_aggr<64><<<nb64, 256, 0, stream>>>(bufA, bufD, dinv, row_off, csr, bufB, -2.f, -1.f, N);
    k_cheb_mm<64><<<nbw, 256, 0, stream>>>(bufD, bufA, bufB, W2, b2, bufC, N);

    // ---- EdgeConv 2
    k_e1<<<nbw, 256, 0, stream>>>(bufC, Wt2, Wp2, bt2, bp2, bufA, bufB, N);
    k_e2<<<nb64, 256, 0, stream>>>(bufA, bufB, row_off, csr, bufD, N);

    // ---- Cheb layer 3
    k_aggr<64><<<nb64, 256, 0, stream>>>(bufD, nullptr, dinv, row_off, csr, bufA, -1.f, 0.f, N);
    k_aggr<64><<<nb64, 256, 0, stream>>>(bufA, bufD, dinv, row_off, csr, bufB, -2.f, -1.f, N);
    k_cheb_mm<64><<<nbw, 256, 0, stream>>>(bufD, bufA, bufB, W3, b3, bufC, N);

    // ---- per-graph mean pooling
    k_pool<<<npool, 256, 0, stream>>>(bufC, gid, out, gcnt, N);
    k_div<<<(out_size + 255) / 256, 256, 0, stream>>>(out, gcnt, out_size);
}

// Round 3
// 1598.868 us; speedup vs baseline: 1.4304x; 1.0856x over previous
//
#include <hip/hip_runtime.h>
#include <hip/hip_bf16.h>
#include <math.h>

// ---------------- CSR build ----------------

__global__ __launch_bounds__(256) void k_hist(const int* __restrict__ dst, int* __restrict__ cnt, int E) {
    int i = blockIdx.x * blockDim.x + threadIdx.x;
    if (i < E) atomicAdd(&cnt[dst[i]], 1);
}

__global__ __launch_bounds__(256) void k_scanA(const int* __restrict__ cnt, int* __restrict__ bsum, int N) {
    __shared__ int s[256];
    int t = threadIdx.x;
    int i = blockIdx.x * 256 + t;
    s[t] = (i < N) ? cnt[i] : 0;
    __syncthreads();
    for (int off = 128; off > 0; off >>= 1) {
        if (t < off) s[t] += s[t + off];
        __syncthreads();
    }
    if (t == 0) bsum[blockIdx.x] = s[0];
}

__global__ __launch_bounds__(512) void k_scanB(int* __restrict__ bsum, int B) {
    __shared__ int s[512];
    int t = threadIdx.x;
    int v = (t < B) ? bsum[t] : 0;
    s[t] = v;
    __syncthreads();
    for (int off = 1; off < 512; off <<= 1) {
        int x = (t >= off) ? s[t - off] : 0;
        __syncthreads();
        s[t] += x;
        __syncthreads();
    }
    if (t < B) bsum[t] = s[t] - v;   // exclusive
}

__global__ __launch_bounds__(256) void k_scanC(const int* __restrict__ cnt, const int* __restrict__ bsum,
                                               int* __restrict__ row_off, int* __restrict__ cursor,
                                               float* __restrict__ dinv, int N, int E) {
    __shared__ int s[256];
    int t = threadIdx.x;
    int i = blockIdx.x * 256 + t;
    int v = (i < N) ? cnt[i] : 0;
    s[t] = v;
    __syncthreads();
    for (int off = 1; off < 256; off <<= 1) {
        int x = (t >= off) ? s[t - off] : 0;
        __syncthreads();
        s[t] += x;
        __syncthreads();
    }
    if (i < N) {
        int excl = bsum[blockIdx.x] + s[t] - v;
        row_off[i] = excl;
        cursor[i]  = excl;
        dinv[i]    = rsqrtf((float)(v > 1 ? v : 1));
    }
    if (i == 0) row_off[N] = E;
}

__global__ __launch_bounds__(256) void k_scatter(const int* __restrict__ src, const int* __restrict__ dst,
                                                 int* __restrict__ cursor, int* __restrict__ csr, int E) {
    int i = blockIdx.x * blockDim.x + threadIdx.x;
    if (i < E) {
        int d = dst[i];
        int pos = atomicAdd(&cursor[d], 1);
        csr[pos] = src[i];
    }
}

// ---------------- Chebyshev aggregation: out = alpha * (dinv[n] * sum_j X[j]*dinv[j]) + beta * Z[n] ----------------

template <int D>
__global__ __launch_bounds__(256) void k_aggr(const float* __restrict__ X, const float* __restrict__ Z,
                                              const float* __restrict__ dinv,
                                              const int* __restrict__ row_off, const int* __restrict__ csr,
                                              float* __restrict__ out, float alpha, float beta, int N) {
    int t = blockIdx.x * blockDim.x + threadIdx.x;
    int node = t / D;
    int d = t % D;
    if (node >= N) return;
    int beg = row_off[node], end = row_off[node + 1];
    float a0 = 0.f, a1 = 0.f, a2 = 0.f, a3 = 0.f;
    int j = beg;
    for (; j + 3 < end; j += 4) {
        int s0 = csr[j], s1 = csr[j + 1], s2 = csr[j + 2], s3 = csr[j + 3];
        a0 += X[s0 * D + d] * dinv[s0];
        a1 += X[s1 * D + d] * dinv[s1];
        a2 += X[s2 * D + d] * dinv[s2];
        a3 += X[s3 * D + d] * dinv[s3];
    }
    for (; j < end; ++j) {
        int s = csr[j];
        a0 += X[s * D + d] * dinv[s];
    }
    float acc = (a0 + a1) + (a2 + a3);
    float v = alpha * dinv[node] * acc;
    if (Z) v += beta * Z[node * D + d];
    out[node * D + d] = v;
}

// ---------------- Cheb matmul: out = relu(b + X0@W[0] + X1@W[1] + X2@W[2]), W[k][i][o] ----------------
// Grid-stride over nodes: each block stages the 3*K*64 weights into LDS ONCE, then
// sweeps many nodes per wave (weight staging was 12288 loads per 4 nodes before).

template <int K>
__global__ __launch_bounds__(256) void k_cheb_mm(const float* __restrict__ X0, const float* __restrict__ X1,
                                                 const float* __restrict__ X2, const float* __restrict__ W,
                                                 const float* __restrict__ b, float* __restrict__ out, int N) {
    __shared__ float Ws[3 * K * 64];
    int t = threadIdx.x;
    for (int idx = t; idx < 3 * K * 64; idx += 256) Ws[idx] = W[idx];
    __syncthreads();
    int wave = t >> 6, lane = t & 63;
    int gw = blockIdx.x * 4 + wave;
    int nw = gridDim.x * 4;
    float bias = b[lane];
    for (int node = gw; node < N; node += nw) {
        float v0 = 0.f, v1 = 0.f, v2 = 0.f;
        if (lane < K) {
            v0 = X0[node * K + lane];
            v1 = X1[node * K + lane];
            v2 = X2[node * K + lane];
        }
        float acc = bias;
#pragma unroll
        for (int i = 0; i < K; ++i) {
            float x0 = __shfl(v0, i), x1 = __shfl(v1, i), x2 = __shfl(v2, i);
            acc += x0 * Ws[i * 64 + lane] + x1 * Ws[(K + i) * 64 + lane] + x2 * Ws[(2 * K + i) * 64 + lane];
        }
        out[node * 64 + lane] = fmaxf(acc, 0.f);
    }
}

// ---------------- EdgeConv stage 1: m = X@Wt ; p = X@(Wt+Wp) + bt + bp ----------------

__global__ __launch_bounds__(256) void k_e1(const float* __restrict__ X, const float* __restrict__ Wt,
                                            const float* __restrict__ Wp, const float* __restrict__ bt,
                                            const float* __restrict__ bp, float* __restrict__ m,
                                            float* __restrict__ pbuf, int N) {
    __shared__ float Wts[64 * 64];
    __shared__ float Wps[64 * 64];
    int t = threadIdx.x;
    for (int idx = t; idx < 4096; idx += 256) {
        Wts[idx] = Wt[idx];
        Wps[idx] = Wp[idx];
    }
    __syncthreads();
    int wave = t >> 6, lane = t & 63;
    int gw = blockIdx.x * 4 + wave;
    int nw = gridDim.x * 4;
    float bias = bt[lane] + bp[lane];
    for (int node = gw; node < N; node += nw) {
        float v = X[node * 64 + lane];
        float am = 0.f, ap = bias;
#pragma unroll
        for (int i = 0; i < 64; ++i) {
            float xi = __shfl(v, i);
            float wt = Wts[i * 64 + lane];
            am += xi * wt;
            ap += xi * (wt + Wps[i * 64 + lane]);
        }
        m[node * 64 + lane] = am;
        pbuf[node * 64 + lane] = ap;
    }
}

// ---------------- EdgeConv stage 2: out = relu(p[n] + max_j(-m[src_j])), 0 if no in-edges ----------------

__global__ __launch_bounds__(256) void k_e2(const float* __restrict__ m, const float* __restrict__ pbuf,
                                            const int* __restrict__ row_off, const int* __restrict__ csr,
                                            float* __restrict__ out, int N) {
    int t = blockIdx.x * blockDim.x + threadIdx.x;
    int node = t >> 6;
    int d = t & 63;
    if (node >= N) return;
    int beg = row_off[node], end = row_off[node + 1];
    float a0 = -INFINITY, a1 = -INFINITY, a2 = -INFINITY, a3 = -INFINITY;
    int j = beg;
    for (; j + 3 < end; j += 4) {
        int s0 = csr[j], s1 = csr[j + 1], s2 = csr[j + 2], s3 = csr[j + 3];
        a0 = fmaxf(a0, -m[s0 * 64 + d]);
        a1 = fmaxf(a1, -m[s1 * 64 + d]);
        a2 = fmaxf(a2, -m[s2 * 64 + d]);
        a3 = fmaxf(a3, -m[s3 * 64 + d]);
    }
    for (; j < end; ++j) {
        int s = csr[j];
        a0 = fmaxf(a0, -m[s * 64 + d]);
    }
    float r = 0.f;
    if (end > beg) r = fmaxf(pbuf[node * 64 + d] + fmaxf(fmaxf(a0, a1), fmaxf(a2, a3)), 0.f);
    out[node * 64 + d] = r;
}

// ---------------- graph mean pooling (segmented: gid is sorted) ----------------

__global__ __launch_bounds__(256) void k_pool(const float* __restrict__ h, const int* __restrict__ gid,
                                              float* __restrict__ out, float* __restrict__ gcnt, int N) {
    const int CHUNK = 128;
    int wave = blockIdx.x * 4 + (threadIdx.x >> 6);
    int lane = threadIdx.x & 63;
    int beg = wave * CHUNK;
    if (beg >= N) return;
    int end = beg + CHUNK < N ? beg + CHUNK : N;
    int gcur = gid[beg];
    float acc = 0.f;
    int cnt = 0;
    for (int n = beg; n < end; ++n) {
        int g = gid[n];
        float v = h[n * 64 + lane];
        if (g != gcur) {
            atomicAdd(&out[gcur * 64 + lane], acc);
            if (lane == 0) atomicAdd(&gcnt[gcur], (float)cnt);
            gcur = g; acc = 0.f; cnt = 0;
        }
        acc += v;
        ++cnt;
    }
    atomicAdd(&out[gcur * 64 + lane], acc);
    if (lane == 0) atomicAdd(&gcnt[gcur], (float)cnt);
}

__global__ __launch_bounds__(256) void k_div(float* __restrict__ out, const float* __restrict__ gcnt, int total) {
    int i = blockIdx.x * blockDim.x + threadIdx.x;
    if (i < total) out[i] /= fmaxf(gcnt[i >> 6], 1.f);
}

// ---------------- launcher ----------------

extern "C" void kernel_launch(void* const* d_in, const int* in_sizes, int n_in,
                              void* d_out, int out_size, void* d_ws, size_t ws_size,
                              hipStream_t stream) {
    const float* feat = (const float*)d_in[0];
    const int* src = (const int*)d_in[1];
    const int* dst = (const int*)d_in[2];
    const int* gid = (const int*)d_in[3];
    const float* W1 = (const float*)d_in[4];  const float* b1 = (const float*)d_in[5];
    const float* W2 = (const float*)d_in[6];  const float* b2 = (const float*)d_in[7];
    const float* W3 = (const float*)d_in[8];  const float* b3 = (const float*)d_in[9];
    const float* Wt1 = (const float*)d_in[10]; const float* bt1 = (const float*)d_in[11];
    const float* Wp1 = (const float*)d_in[12]; const float* bp1 = (const float*)d_in[13];
    const float* Wt2 = (const float*)d_in[14]; const float* bt2 = (const float*)d_in[15];
    const float* Wp2 = (const float*)d_in[16]; const float* bp2 = (const float*)d_in[17];
    float* out = (float*)d_out;

    const int N = in_sizes[0] / 16;
    const int E = in_sizes[1];
    const int G = out_size / 64;

    char* p = (char*)d_ws;
    auto alloc = [&](size_t nbytes) {
        void* r = (void*)p;
        p += (nbytes + 255) & ~(size_t)255;
        return r;
    };
    int* cnt      = (int*)alloc((size_t)N * 4);
    int* row_off  = (int*)alloc((size_t)(N + 1) * 4);
    int* cursor   = (int*)alloc((size_t)N * 4);
    int* csr      = (int*)alloc((size_t)E * 4);
    int* bsum     = (int*)alloc(512 * 4);
    float* dinv   = (float*)alloc((size_t)N * 4);
    float* bufA   = (float*)alloc((size_t)N * 64 * 4);
    float* bufB   = (float*)alloc((size_t)N * 64 * 4);
    float* bufC   = (float*)alloc((size_t)N * 64 * 4);
    float* bufD   = (float*)alloc((size_t)N * 64 * 4);
    float* gcnt   = (float*)alloc((size_t)G * 4);

    hipMemsetAsync(cnt, 0, (size_t)N * 4, stream);
    hipMemsetAsync(gcnt, 0, (size_t)G * 4, stream);
    hipMemsetAsync(d_out, 0, (size_t)out_size * 4, stream);

    const int B = (N + 255) / 256;
    const int ebk = (E + 255) / 256;
    const int nb64 = (N * 64 + 255) / 256;
    const int nb16 = (N * 16 + 255) / 256;
    const int npool = ((N + 127) / 128 + 3) / 4;

    // dense-matmul grids: fixed size, grid-stride over nodes (weights staged once/block)
    const int g_cheb64 = 768;   // 48KB LDS -> 3 blocks/CU, 256 CUs
    const int g_cheb16 = 1024;  // 12KB LDS
    const int g_e1     = 1024;  // 32KB LDS -> 5 blocks/CU

    k_hist<<<ebk, 256, 0, stream>>>(dst, cnt, E);
    k_scanA<<<B, 256, 0, stream>>>(cnt, bsum, N);
    k_scanB<<<1, 512, 0, stream>>>(bsum, B);
    k_scanC<<<B, 256, 0, stream>>>(cnt, bsum, row_off, cursor, dinv, N, E);
    k_scatter<<<ebk, 256, 0, stream>>>(src, dst, cursor, csr, E);

    // ---- Cheb layer 1 (IN=16) : X1 = -aggr(X0); X2 = -2*aggr(X1) - X0
    k_aggr<16><<<nb16, 256, 0, stream>>>(feat, nullptr, dinv, row_off, csr, bufA, -1.f, 0.f, N);
    k_aggr<16><<<nb16, 256, 0, stream>>>(bufA, feat, dinv, row_off, csr, bufB, -2.f, -1.f, N);
    k_cheb_mm<16><<<g_cheb16, 256, 0, stream>>>(feat, bufA, bufB, W1, b1, bufC, N);

    // ---- EdgeConv 1
    k_e1<<<g_e1, 256, 0, stream>>>(bufC, Wt1, Wp1, bt1, bp1, bufA, bufB, N);
    k_e2<<<nb64, 256, 0, stream>>>(bufA, bufB, row_off, csr, bufD, N);

    // ---- Cheb layer 2
    k_aggr<64><<<nb64, 256, 0, stream>>>(bufD, nullptr, dinv, row_off, csr, bufA, -1.f, 0.f, N);
    k_aggr<64><<<nb64, 256, 0, stream>>>(bufA, bufD, dinv, row_off, csr, bufB, -2.f, -1.f, N);
    k_cheb_mm<64><<<g_cheb64, 256, 0, stream>>>(bufD, bufA, bufB, W2, b2, bufC, N);

    // ---- EdgeConv 2
    k_e1<<<g_e1, 256, 0, stream>>>(bufC, Wt2, Wp2, bt2, bp2, bufA, bufB, N);
    k_e2<<<nb64, 256, 0, stream>>>(bufA, bufB, row_off, csr, bufD, N);

    // ---- Cheb layer 3
    k_aggr<64><<<nb64, 256, 0, stream>>>(bufD, nullptr, dinv, row_off, csr, bufA, -1.f, 0.f, N);
    k_aggr<64><<<nb64, 256, 0, stream>>>(bufA, bufD, dinv, row_off, csr, bufB, -2.f, -1.f, N);
    k_cheb_mm<64><<<g_cheb64, 256, 0, stream>>>(bufD, bufA, bufB, W3, b3, bufC, N);

    // ---- per-graph mean pooling
    k_pool<<<npool, 256, 0, stream>>>(bufC, gid, out, gcnt, N);
    k_div<<<(out_size + 255) / 256, 256, 0, stream>>>(out, gcnt, out_size);
}